// Round 4
// baseline (1309.963 us; speedup 1.0000x reference)
//
#include <hip/hip_runtime.h>
#include <cstdint>

#define HH 128
#define SV 132  // padded f32 LDS row stride for GEMM A tiles
constexpr int cN_X   = 250000;
constexpr int cN_SRC = 50000;
constexpr int cN_Y   = 50000;
constexpr int cN_INT = 500000;
constexpr int cE_NODE = 1000000;
constexpr int cE_DOM  = 500000;

typedef __attribute__((ext_vector_type(8))) short bf16x8;
typedef __attribute__((ext_vector_type(4))) float f32x4;

__device__ __forceinline__ float bf2f(unsigned short s) {
  union { unsigned u; float f; } v; v.u = ((unsigned)s) << 16; return v.f;
}
__device__ __forceinline__ unsigned short f2bf(float f) {
  union { float f; unsigned u; } v; v.f = f;
  unsigned r = v.u + 0x7fffu + ((v.u >> 16) & 1u);  // RNE
  return (unsigned short)(r >> 16);
}

// ---------------- cast the three W matrices to bf16 (row-major) once
__global__ __launch_bounds__(256) void k_wcast(const float* __restrict__ w0,
                                               const float* __restrict__ w1,
                                               const float* __restrict__ w2,
                                               unsigned short* __restrict__ dst) {
  int i = blockIdx.x * 256 + threadIdx.x;
  int idx4 = i * 4;
  int mat = idx4 >> 14;
  int off = idx4 & 16383;
  const float* src = (mat == 0) ? w0 : (mat == 1) ? w1 : w2;
  float4 v = *(const float4*)(src + off);
  ushort4 u;
  u.x = f2bf(v.x); u.y = f2bf(v.y); u.z = f2bf(v.z); u.w = f2bf(v.w);
  *(ushort4*)(dst + (size_t)mat * 16384 + off) = u;
}

// ---------------- segment-sum of x by sorted domain_indicator -> xsum [N_SRC][H]
// wave owns 32 rows; 8-deep float2 load batches for latency hiding.
__global__ __launch_bounds__(256, 4) void k_segsum_x(const float* __restrict__ x,
                                                     const int* __restrict__ ind,
                                                     float* __restrict__ xsum) {
  __shared__ int sind[128];
  int tid = threadIdx.x, lane = tid & 63, wv = tid >> 6;
  int blk = blockIdx.x * 128;
  if (tid < 128 && blk + tid < cN_X) sind[tid] = ind[blk + tid];
  __syncthreads();
  int base = blk + wv * 32;
  if (base >= cN_X) return;
  int nrows = min(32, cN_X - base);
  int c0 = lane * 2;
  float a0 = 0.f, a1 = 0.f;
  int cur = sind[wv * 32];
  bool inside = false;
  for (int r0 = 0; r0 < nrows; r0 += 8) {
    int nb = min(8, nrows - r0);
    float2 v[8];
#pragma unroll
    for (int k = 0; k < 8; k++)
      if (k < nb) v[k] = *(const float2*)(x + (size_t)(base + r0 + k) * HH + c0);
#pragma unroll
    for (int k = 0; k < 8; k++) {
      if (k < nb) {
        int s = sind[wv * 32 + r0 + k];
        if (s != cur) {
          if (inside) {
            xsum[(size_t)cur * HH + c0] = a0;
            xsum[(size_t)cur * HH + c0 + 1] = a1;
          } else {
            atomicAdd(&xsum[(size_t)cur * HH + c0], a0);
            atomicAdd(&xsum[(size_t)cur * HH + c0 + 1], a1);
          }
          cur = s; a0 = 0.f; a1 = 0.f; inside = true;
        }
        a0 += v[k].x; a1 += v[k].y;
      }
    }
  }
  atomicAdd(&xsum[(size_t)cur * HH + c0], a0);
  atomicAdd(&xsum[(size_t)cur * HH + c0 + 1], a1);
}

// ---------------- MFMA helpers
__device__ __forceinline__ void load_bfrags(const unsigned short* __restrict__ Wbf,
                                            int wv, int lane, bf16x8 bfrag[2][4]) {
  int cbase = wv * 32 + (lane & 15);
  int krow = (lane >> 4) * 8;
#pragma unroll
  for (int ct = 0; ct < 2; ct++)
#pragma unroll
    for (int kt = 0; kt < 4; kt++)
      bfrag[ct][kt] = *(const bf16x8*)(Wbf + (size_t)(cbase + ct * 16) * HH + kt * 32 + krow);
}

__device__ __forceinline__ bf16x8 make_afrag(const float* __restrict__ ap) {
  f32x4 f0 = *(const f32x4*)ap;
  f32x4 f1 = *(const f32x4*)(ap + 4);
  bf16x8 a;
  a[0] = (short)f2bf(f0[0]); a[1] = (short)f2bf(f0[1]);
  a[2] = (short)f2bf(f0[2]); a[3] = (short)f2bf(f0[3]);
  a[4] = (short)f2bf(f1[0]); a[5] = (short)f2bf(f1[1]);
  a[6] = (short)f2bf(f1[2]); a[7] = (short)f2bf(f1[3]);
  return a;
}

// ---------------- outb[M][128] (bf16) = A[M][128] @ W^T via MFMA
__global__ __launch_bounds__(256, 4) void k_gemm128b(const float* __restrict__ A,
                                                     const unsigned short* __restrict__ Wbf,
                                                     unsigned short* __restrict__ outb, int M) {
  __shared__ float sA[64 * SV];
  int tid = threadIdx.x, lane = tid & 63, wv = tid >> 6;
  int row0 = blockIdx.x * 64;
  int rows = min(64, M - row0);
  bf16x8 bfrag[2][4];
  load_bfrags(Wbf, wv, lane, bfrag);
  for (int i = tid; i < 64 * 32; i += 256) {
    int idx = i * 4, r = idx >> 7, c = idx & 127;
    f32x4 v = {0.f, 0.f, 0.f, 0.f};
    if (r < rows) {
      float4 g = *(const float4*)(A + (size_t)(row0 + r) * HH + c);
      v[0] = g.x; v[1] = g.y; v[2] = g.z; v[3] = g.w;
    }
    *(f32x4*)(&sA[r * SV + c]) = v;
  }
  __syncthreads();
  int m = lane & 15, q = lane >> 4;
  f32x4 acc[4][2];
#pragma unroll
  for (int rt = 0; rt < 4; rt++)
#pragma unroll
    for (int ct = 0; ct < 2; ct++) acc[rt][ct] = (f32x4){0.f, 0.f, 0.f, 0.f};
#pragma unroll
  for (int kt = 0; kt < 4; kt++) {
    int kof = kt * 32 + q * 8;
#pragma unroll
    for (int rt = 0; rt < 4; rt++) {
      bf16x8 af = make_afrag(&sA[(rt * 16 + m) * SV + kof]);
      acc[rt][0] = __builtin_amdgcn_mfma_f32_16x16x32_bf16(af, bfrag[0][kt], acc[rt][0], 0, 0, 0);
      acc[rt][1] = __builtin_amdgcn_mfma_f32_16x16x32_bf16(af, bfrag[1][kt], acc[rt][1], 0, 0, 0);
    }
  }
  __syncthreads();
  unsigned short* sC = (unsigned short*)sA;
#pragma unroll
  for (int rt = 0; rt < 4; rt++)
#pragma unroll
    for (int ct = 0; ct < 2; ct++)
#pragma unroll
      for (int rg = 0; rg < 4; rg++) {
        int r = rt * 16 + q * 4 + rg;
        sC[r * HH + wv * 32 + ct * 16 + m] = f2bf(acc[rt][ct][rg]);
      }
  __syncthreads();
  for (int i = tid; i < rows * 16; i += 256) {
    int r = i >> 4, g = i & 15;
    ((uint4*)(outb + (size_t)(row0 + r) * HH))[g] = ((const uint4*)(sC + r * HH))[g];
  }
}

// ---------------- bnd via linear boundary marking (one pass, no binary search)
// bnd[e] = first j with ii[j] >= e
__global__ __launch_bounds__(256) void k_bounds(const int* __restrict__ ii,
                                                int* __restrict__ bnd) {
  int j = blockIdx.x * 256 + threadIdx.x;
  if (j > cE_NODE) return;
  if (j == cE_NODE) {
    int a = ii[cE_NODE - 1];
    for (int e = a + 1; e <= cN_INT; ++e) bnd[e] = cE_NODE;
    return;
  }
  int b = ii[j];
  int a = (j == 0) ? -1 : ii[j - 1];
  for (int e = a + 1; e <= b; ++e) bnd[e] = j;
}

// ---------------- CSR build for dme1
__global__ void k_hist(const int* __restrict__ dme1, int* __restrict__ cnt) {
  int e = blockIdx.x * blockDim.x + threadIdx.x;
  if (e < cE_DOM) atomicAdd(&cnt[dme1[e]], 1);
}
__global__ __launch_bounds__(256) void k_scan1(const int* __restrict__ cnt,
                                               int* __restrict__ bsum, int* __restrict__ excl) {
  __shared__ int buf[256];
  int i = blockIdx.x * 256 + threadIdx.x;
  int v = (i < cN_SRC) ? cnt[i] : 0;
  buf[threadIdx.x] = v; __syncthreads();
  for (int d = 1; d < 256; d <<= 1) {
    int t = (threadIdx.x >= d) ? buf[threadIdx.x - d] : 0;
    __syncthreads();
    buf[threadIdx.x] += t;
    __syncthreads();
  }
  if (i < cN_SRC) excl[i] = buf[threadIdx.x] - v;
  if (threadIdx.x == 255) bsum[blockIdx.x] = buf[255];
}
__global__ __launch_bounds__(256) void k_scan2(int* __restrict__ bsum, int nb) {
  __shared__ int buf[256];
  int v = (threadIdx.x < nb) ? bsum[threadIdx.x] : 0;
  buf[threadIdx.x] = v; __syncthreads();
  for (int d = 1; d < 256; d <<= 1) {
    int t = (threadIdx.x >= d) ? buf[threadIdx.x - d] : 0;
    __syncthreads();
    buf[threadIdx.x] += t;
    __syncthreads();
  }
  if (threadIdx.x < nb) bsum[threadIdx.x] = buf[threadIdx.x] - v;
}
__global__ void k_scan3(const int* __restrict__ excl, const int* __restrict__ bsum,
                        int* __restrict__ offs, int* __restrict__ cursor) {
  int i = blockIdx.x * 256 + threadIdx.x;
  if (i < cN_SRC) { int o = excl[i] + bsum[i >> 8]; offs[i] = o; cursor[i] = o; }
  else if (i == cN_SRC) offs[cN_SRC] = cE_DOM;
}
__global__ void k_scatter(const int* __restrict__ dme1, int* __restrict__ cursor,
                          int* __restrict__ eid) {
  int e = blockIdx.x * blockDim.x + threadIdx.x;
  if (e < cE_DOM) {
    int pos = atomicAdd(&cursor[dme1[e]], 1);
    eid[pos] = e;
  }
}

// ---------------- edge kernel: gather-sum xW rows into 32 bins (+1 dummy pad bin),
// add xsl/ylin gathers, write bf16 msg, BN partials. Deep load batches.
__global__ __launch_bounds__(256, 4) void k_edge(
    const unsigned short* __restrict__ xw, const int* __restrict__ nme0,
    const int* __restrict__ ii, const int* __restrict__ bnd,
    const unsigned short* __restrict__ xsl, const unsigned short* __restrict__ yl,
    const int* __restrict__ dme0, const int* __restrict__ dme1,
    unsigned short* __restrict__ msg, float* __restrict__ partials) {
  __shared__ float sV[33 * HH];  // 16.9 KB (row 32 = dummy pad bin)
  __shared__ float sAux[1024];   // 4 KB: sIdx during gather, sBN after
  int* sIdx = (int*)sAux;
  int tid = threadIdx.x, lane = tid & 63, wv = tid >> 6;
  int e0 = blockIdx.x * 32;
  int j0 = bnd[e0], j1 = bnd[e0 + 32];
  int c0 = lane * 2;

  for (int i = tid; i < 33 * HH; i += 256) sV[i] = 0.f;
  __syncthreads();

  const unsigned* xwu = (const unsigned*)xw;
  for (int jb = j0; jb < j1; jb += 256) {
    int cn = min(256, j1 - jb);
    int cnp = (cn + 31) & ~31;  // pad so each wave's row count is a multiple of 8
    sIdx[tid] = (tid < cn) ? nme0[jb + tid] : 0;
    sIdx[256 + tid] = (tid < cn) ? (ii[jb + tid] - e0) : 32;
    __syncthreads();
    for (int p = wv; p < cnp; p += 32) {
      int r[8], b[8];
      unsigned u[8];
#pragma unroll
      for (int k = 0; k < 8; k++) { r[k] = sIdx[p + 4 * k]; b[k] = sIdx[256 + p + 4 * k]; }
#pragma unroll
      for (int k = 0; k < 8; k++) u[k] = xwu[(size_t)r[k] * 64 + lane];
#pragma unroll
      for (int k = 0; k < 8; k++) {
        atomicAdd(&sV[b[k] * HH + c0], bf2f(u[k] & 0xffff));
        atomicAdd(&sV[b[k] * HH + c0 + 1], bf2f(u[k] >> 16));
      }
    }
    __syncthreads();
  }
  __syncthreads();

  // epilogue: per wave, coalesced dme load + shfl broadcast; 16 gathers in flight
  int dv = (lane < 32) ? dme0[e0 + lane] : dme1[e0 + lane - 32];
  const unsigned* xslu = (const unsigned*)xsl;
  const unsigned* ylu = (const unsigned*)yl;
  int ss[8], tt[8];
  unsigned xs[8], yy[8];
#pragma unroll
  for (int i = 0; i < 8; i++) {
    int le = wv * 8 + i;
    ss[i] = __shfl(dv, le);
    tt[i] = __shfl(dv, 32 + le);
  }
#pragma unroll
  for (int i = 0; i < 8; i++) xs[i] = xslu[(size_t)ss[i] * 64 + lane];
#pragma unroll
  for (int i = 0; i < 8; i++) yy[i] = ylu[(size_t)tt[i] * 64 + lane];
  float s0 = 0.f, s1 = 0.f, q0 = 0.f, q1 = 0.f;
#pragma unroll
  for (int i = 0; i < 8; i++) {
    int le = wv * 8 + i;
    int e = e0 + le;
    float m0 = sV[le * HH + c0] + bf2f(xs[i] & 0xffff) + bf2f(yy[i] & 0xffff);
    float m1 = sV[le * HH + c0 + 1] + bf2f(xs[i] >> 16) + bf2f(yy[i] >> 16);
    ushort2 u; u.x = f2bf(m0); u.y = f2bf(m1);
    *(ushort2*)(msg + (size_t)e * HH + c0) = u;
    s0 += m0; q0 += m0 * m0; s1 += m1; q1 += m1 * m1;
  }
  __syncthreads();
  float* sBN = sAux;
  *(float4*)(&sBN[wv * 256 + lane * 4]) = make_float4(s0, q0, s1, q1);
  __syncthreads();
  partials[(size_t)blockIdx.x * 256 + tid] =
      sBN[tid] + sBN[256 + tid] + sBN[512 + tid] + sBN[768 + tid];
}

// ---------------- BN stat reduction + scale/shift
__global__ __launch_bounds__(256) void k_bnred1(const float* __restrict__ partials,
                                                float* __restrict__ part2, int nb) {
  float s = 0.f;
  for (int b = blockIdx.x; b < nb; b += 64) s += partials[(size_t)b * 256 + threadIdx.x];
  part2[blockIdx.x * 256 + threadIdx.x] = s;
}
__global__ __launch_bounds__(256) void k_bnfinal(const float* __restrict__ part2,
                                                 const float* __restrict__ bnw,
                                                 const float* __restrict__ bnb,
                                                 float* __restrict__ ss) {
  __shared__ float L[256];
  float s = 0.f;
  for (int b = 0; b < 64; b++) s += part2[b * 256 + threadIdx.x];
  L[threadIdx.x] = s; __syncthreads();
  if (threadIdx.x < HH) {
    int c = threadIdx.x;
    float sum = L[2 * c], sq = L[2 * c + 1];
    float mean = sum / (float)cE_DOM;
    float var = sq / (float)cE_DOM - mean * mean;
    float sc = bnw[c] * rsqrtf(var + 1e-5f);
    float sh = bnb[c] - mean * sc;
    ss[2 * c] = sc; ss[2 * c + 1] = sh;
  }
}

// ---------------- final: one wave per target; coalesced eid load + shfl; 4 msg
// rows in flight per batch.
__global__ __launch_bounds__(256, 4) void k_out(const unsigned short* __restrict__ msg,
                                                const int* __restrict__ offs,
                                                const int* __restrict__ eid,
                                                const float* __restrict__ ss,
                                                float* __restrict__ out) {
  int wv = threadIdx.x >> 6, lane = threadIdx.x & 63;
  int t = blockIdx.x * 4 + wv;
  if (t >= cN_Y) return;
  int c0 = lane * 2;
  float sc0 = ss[c0 * 2 + 0], sh0 = ss[c0 * 2 + 1];
  float sc1 = ss[(c0 + 1) * 2 + 0], sh1 = ss[(c0 + 1) * 2 + 1];
  float a0 = 0.f, a1 = 0.f;
  int j0 = offs[t], j1 = offs[t + 1];
  const unsigned* msgu = (const unsigned*)msg;
  for (int jb = j0; jb < j1; jb += 64) {
    int l = min(64, j1 - jb);
    int ee = (lane < l) ? eid[jb + lane] : 0;
    int k = 0;
    for (; k + 3 < l; k += 4) {
      int f0 = __shfl(ee, k), f1 = __shfl(ee, k + 1);
      int f2 = __shfl(ee, k + 2), f3 = __shfl(ee, k + 3);
      unsigned m0 = msgu[(size_t)f0 * 64 + lane];
      unsigned m1 = msgu[(size_t)f1 * 64 + lane];
      unsigned m2 = msgu[(size_t)f2 * 64 + lane];
      unsigned m3 = msgu[(size_t)f3 * 64 + lane];
      a0 += fmaxf(fmaf(bf2f(m0 & 0xffff), sc0, sh0), 0.f);
      a1 += fmaxf(fmaf(bf2f(m0 >> 16), sc1, sh1), 0.f);
      a0 += fmaxf(fmaf(bf2f(m1 & 0xffff), sc0, sh0), 0.f);
      a1 += fmaxf(fmaf(bf2f(m1 >> 16), sc1, sh1), 0.f);
      a0 += fmaxf(fmaf(bf2f(m2 & 0xffff), sc0, sh0), 0.f);
      a1 += fmaxf(fmaf(bf2f(m2 >> 16), sc1, sh1), 0.f);
      a0 += fmaxf(fmaf(bf2f(m3 & 0xffff), sc0, sh0), 0.f);
      a1 += fmaxf(fmaf(bf2f(m3 >> 16), sc1, sh1), 0.f);
    }
    for (; k < l; k++) {
      int f0 = __shfl(ee, k);
      unsigned m0 = msgu[(size_t)f0 * 64 + lane];
      a0 += fmaxf(fmaf(bf2f(m0 & 0xffff), sc0, sh0), 0.f);
      a1 += fmaxf(fmaf(bf2f(m0 >> 16), sc1, sh1), 0.f);
    }
  }
  *(float2*)(out + (size_t)t * HH + c0) = make_float2(a0, a1);
}

extern "C" void kernel_launch(void* const* d_in, const int* in_sizes, int n_in,
                              void* d_out, int out_size, void* d_ws, size_t ws_size,
                              hipStream_t stream) {
  const float* x     = (const float*)d_in[0];
  const float* y     = (const float*)d_in[1];
  const int* dom_ind = (const int*)d_in[2];
  const int* nme     = (const int*)d_in[3];
  const int* ii      = (const int*)d_in[4];
  const int* dme     = (const int*)d_in[5];
  const float* Wxsum = (const float*)d_in[6];
  const float* Wxint = (const float*)d_in[7];
  const float* Wy    = (const float*)d_in[8];
  const float* bnw   = (const float*)d_in[9];
  const float* bnb   = (const float*)d_in[10];
  float* out = (float*)d_out;

  char* ws = (char*)d_ws;
  size_t o = 0;
  auto alloc = [&](size_t bytes) -> void* {
    void* p = ws + o;
    o = (o + bytes + 255) & ~(size_t)255;
    return p;
  };
  float* xsum   = (float*)alloc((size_t)cN_SRC * HH * 4);
  unsigned short* xsl = (unsigned short*)alloc((size_t)cN_SRC * HH * 2);
  unsigned short* ylin = (unsigned short*)alloc((size_t)cN_Y * HH * 2);
  unsigned short* xw = (unsigned short*)alloc((size_t)cN_X * HH * 2);
  unsigned short* msg = (unsigned short*)alloc((size_t)cE_DOM * HH * 2);
  int* bnd      = (int*)alloc((size_t)(cN_INT + 1) * 4);
  int* cnt      = (int*)alloc((size_t)cN_SRC * 4);
  int* excl     = (int*)alloc((size_t)cN_SRC * 4);
  int* bsum     = (int*)alloc(256 * 4);
  int* offs     = (int*)alloc((size_t)(cN_SRC + 1) * 4);
  int* cursor   = (int*)alloc((size_t)cN_SRC * 4);
  int* eid      = (int*)alloc((size_t)cE_DOM * 4);
  const int neb = cE_DOM / 32;  // 15625 edge blocks
  float* partials = (float*)alloc((size_t)neb * 256 * 4);
  float* part2  = (float*)alloc(64 * 256 * 4);
  float* ssbuf  = (float*)alloc(256 * 4);
  unsigned short* Wbf = (unsigned short*)alloc(3 * 16384 * 2);

  hipMemsetAsync(xsum, 0, (size_t)cN_SRC * HH * 4, stream);
  hipMemsetAsync(cnt, 0, (size_t)cN_SRC * 4, stream);

  k_wcast<<<48, 256, 0, stream>>>(Wxsum, Wy, Wxint, Wbf);
  k_segsum_x<<<(cN_X + 127) / 128, 256, 0, stream>>>(x, dom_ind, xsum);
  k_gemm128b<<<(cN_X + 63) / 64, 256, 0, stream>>>(x, Wbf + 32768, xw, cN_X);
  k_gemm128b<<<(cN_SRC + 63) / 64, 256, 0, stream>>>(xsum, Wbf, xsl, cN_SRC);
  k_gemm128b<<<(cN_Y + 63) / 64, 256, 0, stream>>>(y, Wbf + 16384, ylin, cN_Y);
  k_bounds<<<(cE_NODE + 1 + 255) / 256, 256, 0, stream>>>(ii, bnd);
  k_hist<<<(cE_DOM + 255) / 256, 256, 0, stream>>>(dme + cE_DOM, cnt);
  k_scan1<<<(cN_SRC + 255) / 256, 256, 0, stream>>>(cnt, bsum, excl);
  k_scan2<<<1, 256, 0, stream>>>(bsum, (cN_SRC + 255) / 256);
  k_scan3<<<(cN_SRC + 1 + 255) / 256, 256, 0, stream>>>(excl, bsum, offs, cursor);
  k_scatter<<<(cE_DOM + 255) / 256, 256, 0, stream>>>(dme + cE_DOM, cursor, eid);
  k_edge<<<neb, 256, 0, stream>>>(xw, nme, ii, bnd, xsl, ylin,
                                  dme, dme + cE_DOM, msg, partials);
  k_bnred1<<<64, 256, 0, stream>>>(partials, part2, neb);
  k_bnfinal<<<1, 256, 0, stream>>>(part2, bnw, bnb, ssbuf);
  k_out<<<(cN_Y + 3) / 4, 256, 0, stream>>>(msg, offs, eid, ssbuf, out);
}

// Round 5
// 636.828 us; speedup vs baseline: 2.0570x; 2.0570x over previous
//
#include <hip/hip_runtime.h>
#include <cstdint>

#define HH 128
#define SV 132  // padded f32 LDS row stride for GEMM A tiles
constexpr int cN_X   = 250000;
constexpr int cN_SRC = 50000;
constexpr int cN_Y   = 50000;
constexpr int cN_INT = 500000;
constexpr int cE_NODE = 1000000;
constexpr int cE_DOM  = 500000;

typedef __attribute__((ext_vector_type(8))) short bf16x8;
typedef __attribute__((ext_vector_type(4))) float f32x4;

__device__ __forceinline__ float bf2f(unsigned short s) {
  union { unsigned u; float f; } v; v.u = ((unsigned)s) << 16; return v.f;
}
__device__ __forceinline__ unsigned short f2bf(float f) {
  union { float f; unsigned u; } v; v.f = f;
  unsigned r = v.u + 0x7fffu + ((v.u >> 16) & 1u);  // RNE
  return (unsigned short)(r >> 16);
}

// ---------------- cast the three W matrices to bf16 (row-major) once
__global__ __launch_bounds__(256) void k_wcast(const float* __restrict__ w0,
                                               const float* __restrict__ w1,
                                               const float* __restrict__ w2,
                                               unsigned short* __restrict__ dst) {
  int i = blockIdx.x * 256 + threadIdx.x;
  int idx4 = i * 4;
  int mat = idx4 >> 14;
  int off = idx4 & 16383;
  const float* src = (mat == 0) ? w0 : (mat == 1) ? w1 : w2;
  float4 v = *(const float4*)(src + off);
  ushort4 u;
  u.x = f2bf(v.x); u.y = f2bf(v.y); u.z = f2bf(v.z); u.w = f2bf(v.w);
  *(ushort4*)(dst + (size_t)mat * 16384 + off) = u;
}

// ---------------- segment-sum of x by sorted domain_indicator -> xsum [N_SRC][H]
__global__ __launch_bounds__(256, 4) void k_segsum_x(const float* __restrict__ x,
                                                     const int* __restrict__ ind,
                                                     float* __restrict__ xsum) {
  __shared__ int sind[128];
  int tid = threadIdx.x, lane = tid & 63, wv = tid >> 6;
  int blk = blockIdx.x * 128;
  if (tid < 128 && blk + tid < cN_X) sind[tid] = ind[blk + tid];
  __syncthreads();
  int base = blk + wv * 32;
  if (base >= cN_X) return;
  int nrows = min(32, cN_X - base);
  int c0 = lane * 2;
  float a0 = 0.f, a1 = 0.f;
  int cur = sind[wv * 32];
  bool inside = false;
  for (int r0 = 0; r0 < nrows; r0 += 8) {
    int nb = min(8, nrows - r0);
    float2 v[8];
#pragma unroll
    for (int k = 0; k < 8; k++)
      if (k < nb) v[k] = *(const float2*)(x + (size_t)(base + r0 + k) * HH + c0);
#pragma unroll
    for (int k = 0; k < 8; k++) {
      if (k < nb) {
        int s = sind[wv * 32 + r0 + k];
        if (s != cur) {
          if (inside) {
            xsum[(size_t)cur * HH + c0] = a0;
            xsum[(size_t)cur * HH + c0 + 1] = a1;
          } else {
            atomicAdd(&xsum[(size_t)cur * HH + c0], a0);
            atomicAdd(&xsum[(size_t)cur * HH + c0 + 1], a1);
          }
          cur = s; a0 = 0.f; a1 = 0.f; inside = true;
        }
        a0 += v[k].x; a1 += v[k].y;
      }
    }
  }
  atomicAdd(&xsum[(size_t)cur * HH + c0], a0);
  atomicAdd(&xsum[(size_t)cur * HH + c0 + 1], a1);
}

// ---------------- MFMA helpers
__device__ __forceinline__ void load_bfrags(const unsigned short* __restrict__ Wbf,
                                            int wv, int lane, bf16x8 bfrag[2][4]) {
  int cbase = wv * 32 + (lane & 15);
  int krow = (lane >> 4) * 8;
#pragma unroll
  for (int ct = 0; ct < 2; ct++)
#pragma unroll
    for (int kt = 0; kt < 4; kt++)
      bfrag[ct][kt] = *(const bf16x8*)(Wbf + (size_t)(cbase + ct * 16) * HH + kt * 32 + krow);
}

__device__ __forceinline__ bf16x8 make_afrag(const float* __restrict__ ap) {
  f32x4 f0 = *(const f32x4*)ap;
  f32x4 f1 = *(const f32x4*)(ap + 4);
  bf16x8 a;
  a[0] = (short)f2bf(f0[0]); a[1] = (short)f2bf(f0[1]);
  a[2] = (short)f2bf(f0[2]); a[3] = (short)f2bf(f0[3]);
  a[4] = (short)f2bf(f1[0]); a[5] = (short)f2bf(f1[1]);
  a[6] = (short)f2bf(f1[2]); a[7] = (short)f2bf(f1[3]);
  return a;
}

// ---------------- outb[M][128] (bf16) = A[M][128] @ W^T via MFMA
__global__ __launch_bounds__(256, 4) void k_gemm128b(const float* __restrict__ A,
                                                     const unsigned short* __restrict__ Wbf,
                                                     unsigned short* __restrict__ outb, int M) {
  __shared__ float sA[64 * SV];
  int tid = threadIdx.x, lane = tid & 63, wv = tid >> 6;
  int row0 = blockIdx.x * 64;
  int rows = min(64, M - row0);
  bf16x8 bfrag[2][4];
  load_bfrags(Wbf, wv, lane, bfrag);
  for (int i = tid; i < 64 * 32; i += 256) {
    int idx = i * 4, r = idx >> 7, c = idx & 127;
    f32x4 v = {0.f, 0.f, 0.f, 0.f};
    if (r < rows) {
      float4 g = *(const float4*)(A + (size_t)(row0 + r) * HH + c);
      v[0] = g.x; v[1] = g.y; v[2] = g.z; v[3] = g.w;
    }
    *(f32x4*)(&sA[r * SV + c]) = v;
  }
  __syncthreads();
  int m = lane & 15, q = lane >> 4;
  f32x4 acc[4][2];
#pragma unroll
  for (int rt = 0; rt < 4; rt++)
#pragma unroll
    for (int ct = 0; ct < 2; ct++) acc[rt][ct] = (f32x4){0.f, 0.f, 0.f, 0.f};
#pragma unroll
  for (int kt = 0; kt < 4; kt++) {
    int kof = kt * 32 + q * 8;
#pragma unroll
    for (int rt = 0; rt < 4; rt++) {
      bf16x8 af = make_afrag(&sA[(rt * 16 + m) * SV + kof]);
      acc[rt][0] = __builtin_amdgcn_mfma_f32_16x16x32_bf16(af, bfrag[0][kt], acc[rt][0], 0, 0, 0);
      acc[rt][1] = __builtin_amdgcn_mfma_f32_16x16x32_bf16(af, bfrag[1][kt], acc[rt][1], 0, 0, 0);
    }
  }
  __syncthreads();
  unsigned short* sC = (unsigned short*)sA;
#pragma unroll
  for (int rt = 0; rt < 4; rt++)
#pragma unroll
    for (int ct = 0; ct < 2; ct++)
#pragma unroll
      for (int rg = 0; rg < 4; rg++) {
        int r = rt * 16 + q * 4 + rg;
        sC[r * HH + wv * 32 + ct * 16 + m] = f2bf(acc[rt][ct][rg]);
      }
  __syncthreads();
  for (int i = tid; i < rows * 16; i += 256) {
    int r = i >> 4, g = i & 15;
    ((uint4*)(outb + (size_t)(row0 + r) * HH))[g] = ((const uint4*)(sC + r * HH))[g];
  }
}

// ---------------- bnd via linear boundary marking: bnd[e] = first j with ii[j] >= e
__global__ __launch_bounds__(256) void k_bounds(const int* __restrict__ ii,
                                                int* __restrict__ bnd) {
  int j = blockIdx.x * 256 + threadIdx.x;
  if (j > cE_NODE) return;
  if (j == cE_NODE) {
    int a = ii[cE_NODE - 1];
    for (int e = a + 1; e <= cN_INT; ++e) bnd[e] = cE_NODE;
    return;
  }
  int b = ii[j];
  int a = (j == 0) ? -1 : ii[j - 1];
  for (int e = a + 1; e <= b; ++e) bnd[e] = j;
}

// ---------------- CSR build for dme1 (offs + inverse permutation inv[e]=pos)
__global__ void k_hist(const int* __restrict__ dme1, int* __restrict__ cnt) {
  int e = blockIdx.x * blockDim.x + threadIdx.x;
  if (e < cE_DOM) atomicAdd(&cnt[dme1[e]], 1);
}
__global__ __launch_bounds__(256) void k_scan1(const int* __restrict__ cnt,
                                               int* __restrict__ bsum, int* __restrict__ excl) {
  __shared__ int buf[256];
  int i = blockIdx.x * 256 + threadIdx.x;
  int v = (i < cN_SRC) ? cnt[i] : 0;
  buf[threadIdx.x] = v; __syncthreads();
  for (int d = 1; d < 256; d <<= 1) {
    int t = (threadIdx.x >= d) ? buf[threadIdx.x - d] : 0;
    __syncthreads();
    buf[threadIdx.x] += t;
    __syncthreads();
  }
  if (i < cN_SRC) excl[i] = buf[threadIdx.x] - v;
  if (threadIdx.x == 255) bsum[blockIdx.x] = buf[255];
}
__global__ __launch_bounds__(256) void k_scan2(int* __restrict__ bsum, int nb) {
  __shared__ int buf[256];
  int v = (threadIdx.x < nb) ? bsum[threadIdx.x] : 0;
  buf[threadIdx.x] = v; __syncthreads();
  for (int d = 1; d < 256; d <<= 1) {
    int t = (threadIdx.x >= d) ? buf[threadIdx.x - d] : 0;
    __syncthreads();
    buf[threadIdx.x] += t;
    __syncthreads();
  }
  if (threadIdx.x < nb) bsum[threadIdx.x] = buf[threadIdx.x] - v;
}
__global__ void k_scan3(const int* __restrict__ excl, const int* __restrict__ bsum,
                        int* __restrict__ offs, int* __restrict__ cursor) {
  int i = blockIdx.x * 256 + threadIdx.x;
  if (i < cN_SRC) { int o = excl[i] + bsum[i >> 8]; offs[i] = o; cursor[i] = o; }
  else if (i == cN_SRC) offs[cN_SRC] = cE_DOM;
}
__global__ void k_scatter(const int* __restrict__ dme1, int* __restrict__ cursor,
                          int* __restrict__ inv) {
  int e = blockIdx.x * blockDim.x + threadIdx.x;
  if (e < cE_DOM) inv[e] = atomicAdd(&cursor[dme1[e]], 1);
}

// ---------------- edge kernel v2: wave-per-edge (8 edges/wave), no binning LDS,
// no atomics, no mid-kernel barriers. msg written at CSR position (nt store).
__global__ __launch_bounds__(256, 8) void k_edge2(
    const unsigned* __restrict__ xwu, const int* __restrict__ nme0,
    const int* __restrict__ bnd,
    const unsigned* __restrict__ xslu, const unsigned* __restrict__ ylu,
    const int* __restrict__ dme0, const int* __restrict__ dme1,
    const int* __restrict__ inv,
    unsigned* __restrict__ msgu, float* __restrict__ partials) {
  __shared__ int sB[33], sD0[32], sD1[32], sP[32];
  __shared__ float sBN[1024];
  int tid = threadIdx.x, lane = tid & 63, wv = tid >> 6;
  int e0 = blockIdx.x * 32;
  if (tid < 33) sB[tid] = bnd[e0 + tid];
  else if (tid < 96 && tid >= 64) sD0[tid - 64] = dme0[e0 + tid - 64];
  else if (tid < 160 && tid >= 128) sD1[tid - 128] = dme1[e0 + tid - 128];
  else if (tid < 224 && tid >= 192) sP[tid - 192] = inv[e0 + tid - 192];
  __syncthreads();
  float s0 = 0.f, q0 = 0.f, s1 = 0.f, q1 = 0.f;
#pragma unroll
  for (int i = 0; i < 8; i++) {
    int le = wv * 8 + i;
    int s = sD0[le], t = sD1[le], pos = sP[le];
    int j0 = sB[le], n = sB[le + 1] - j0;
    unsigned xs = xslu[(size_t)s * 64 + lane];
    unsigned yy = ylu[(size_t)t * 64 + lane];
    int idxv = (lane < n) ? nme0[j0 + lane] : 0;
    float a0 = 0.f, a1 = 0.f;
    unsigned u[4];
#pragma unroll
    for (int k = 0; k < 4; k++)
      if (k < n) { int r = __shfl(idxv, k); u[k] = xwu[(size_t)r * 64 + lane]; }
#pragma unroll
    for (int k = 0; k < 4; k++)
      if (k < n) { a0 += bf2f(u[k] & 0xffff); a1 += bf2f(u[k] >> 16); }
    for (int k = 4; k < n; k++) {
      int r = (k < 64) ? __shfl(idxv, k) : nme0[j0 + k];
      unsigned uu = xwu[(size_t)r * 64 + lane];
      a0 += bf2f(uu & 0xffff); a1 += bf2f(uu >> 16);
    }
    float m0 = a0 + bf2f(xs & 0xffff) + bf2f(yy & 0xffff);
    float m1 = a1 + bf2f(xs >> 16) + bf2f(yy >> 16);
    unsigned um = ((unsigned)f2bf(m1) << 16) | (unsigned)f2bf(m0);
    __builtin_nontemporal_store(um, &msgu[(size_t)pos * 64 + lane]);
    s0 += m0; q0 += m0 * m0; s1 += m1; q1 += m1 * m1;
  }
  *(float4*)(&sBN[wv * 256 + lane * 4]) = make_float4(s0, q0, s1, q1);
  __syncthreads();
  float v = sBN[tid] + sBN[256 + tid] + sBN[512 + tid] + sBN[768 + tid];
  __builtin_nontemporal_store(v, &partials[(size_t)blockIdx.x * 256 + tid]);
}

// ---------------- BN stat reduction + scale/shift
__global__ __launch_bounds__(256) void k_bnred1(const float* __restrict__ partials,
                                                float* __restrict__ part2, int nb) {
  float s = 0.f;
  for (int b = blockIdx.x; b < nb; b += 64) s += partials[(size_t)b * 256 + threadIdx.x];
  part2[blockIdx.x * 256 + threadIdx.x] = s;
}
__global__ __launch_bounds__(256) void k_bnfinal(const float* __restrict__ part2,
                                                 const float* __restrict__ bnw,
                                                 const float* __restrict__ bnb,
                                                 float* __restrict__ ss) {
  __shared__ float L[256];
  float s = 0.f;
  for (int b = 0; b < 64; b++) s += part2[b * 256 + threadIdx.x];
  L[threadIdx.x] = s; __syncthreads();
  if (threadIdx.x < HH) {
    int c = threadIdx.x;
    float sum = L[2 * c], sq = L[2 * c + 1];
    float mean = sum / (float)cE_DOM;
    float var = sq / (float)cE_DOM - mean * mean;
    float sc = bnw[c] * rsqrtf(var + 1e-5f);
    float sh = bnb[c] - mean * sc;
    ss[2 * c] = sc; ss[2 * c + 1] = sh;
  }
}

// ---------------- final v2: msg is CSR-ordered, so each target reads a
// CONTIGUOUS run of rows [offs[t], offs[t+1]). Pure streaming.
__global__ __launch_bounds__(256, 8) void k_out2(const unsigned* __restrict__ msgu,
                                                 const int* __restrict__ offs,
                                                 const float* __restrict__ ss,
                                                 float* __restrict__ out) {
  int wv = threadIdx.x >> 6, lane = threadIdx.x & 63;
  int t = blockIdx.x * 4 + wv;
  if (t >= cN_Y) return;
  int c0 = lane * 2;
  float sc0 = ss[c0 * 2 + 0], sh0 = ss[c0 * 2 + 1];
  float sc1 = ss[c0 * 2 + 2], sh1 = ss[c0 * 2 + 3];
  int j0 = offs[t], j1 = offs[t + 1];
  float a0 = 0.f, a1 = 0.f;
  int p = j0;
  for (; p + 4 <= j1; p += 4) {
    unsigned m[4];
#pragma unroll
    for (int k = 0; k < 4; k++) m[k] = msgu[(size_t)(p + k) * 64 + lane];
#pragma unroll
    for (int k = 0; k < 4; k++) {
      a0 += fmaxf(fmaf(bf2f(m[k] & 0xffff), sc0, sh0), 0.f);
      a1 += fmaxf(fmaf(bf2f(m[k] >> 16), sc1, sh1), 0.f);
    }
  }
  for (; p < j1; p++) {
    unsigned m = msgu[(size_t)p * 64 + lane];
    a0 += fmaxf(fmaf(bf2f(m & 0xffff), sc0, sh0), 0.f);
    a1 += fmaxf(fmaf(bf2f(m >> 16), sc1, sh1), 0.f);
  }
  *(float2*)(out + (size_t)t * HH + c0) = make_float2(a0, a1);
}

extern "C" void kernel_launch(void* const* d_in, const int* in_sizes, int n_in,
                              void* d_out, int out_size, void* d_ws, size_t ws_size,
                              hipStream_t stream) {
  const float* x     = (const float*)d_in[0];
  const float* y     = (const float*)d_in[1];
  const int* dom_ind = (const int*)d_in[2];
  const int* nme     = (const int*)d_in[3];
  const int* ii      = (const int*)d_in[4];
  const int* dme     = (const int*)d_in[5];
  const float* Wxsum = (const float*)d_in[6];
  const float* Wxint = (const float*)d_in[7];
  const float* Wy    = (const float*)d_in[8];
  const float* bnw   = (const float*)d_in[9];
  const float* bnb   = (const float*)d_in[10];
  float* out = (float*)d_out;

  char* ws = (char*)d_ws;
  size_t o = 0;
  auto alloc = [&](size_t bytes) -> void* {
    void* p = ws + o;
    o = (o + bytes + 255) & ~(size_t)255;
    return p;
  };
  float* xsum   = (float*)alloc((size_t)cN_SRC * HH * 4);
  unsigned short* xsl = (unsigned short*)alloc((size_t)cN_SRC * HH * 2);
  unsigned short* ylin = (unsigned short*)alloc((size_t)cN_Y * HH * 2);
  unsigned short* xw = (unsigned short*)alloc((size_t)cN_X * HH * 2);
  unsigned short* msg = (unsigned short*)alloc((size_t)cE_DOM * HH * 2);
  int* bnd      = (int*)alloc((size_t)(cN_INT + 1) * 4);
  int* cnt      = (int*)alloc((size_t)cN_SRC * 4);
  int* excl     = (int*)alloc((size_t)cN_SRC * 4);
  int* bsum     = (int*)alloc(256 * 4);
  int* offs     = (int*)alloc((size_t)(cN_SRC + 1) * 4);
  int* cursor   = (int*)alloc((size_t)cN_SRC * 4);
  int* inv      = (int*)alloc((size_t)cE_DOM * 4);
  const int neb = cE_DOM / 32;  // 15625 edge blocks
  float* partials = (float*)alloc((size_t)neb * 256 * 4);
  float* part2  = (float*)alloc(64 * 256 * 4);
  float* ssbuf  = (float*)alloc(256 * 4);
  unsigned short* Wbf = (unsigned short*)alloc(3 * 16384 * 2);

  hipMemsetAsync(xsum, 0, (size_t)cN_SRC * HH * 4, stream);
  hipMemsetAsync(cnt, 0, (size_t)cN_SRC * 4, stream);

  k_wcast<<<48, 256, 0, stream>>>(Wxsum, Wy, Wxint, Wbf);
  k_segsum_x<<<(cN_X + 127) / 128, 256, 0, stream>>>(x, dom_ind, xsum);
  k_gemm128b<<<(cN_X + 63) / 64, 256, 0, stream>>>(x, Wbf + 32768, xw, cN_X);
  k_gemm128b<<<(cN_SRC + 63) / 64, 256, 0, stream>>>(xsum, Wbf, xsl, cN_SRC);
  k_gemm128b<<<(cN_Y + 63) / 64, 256, 0, stream>>>(y, Wbf + 16384, ylin, cN_Y);
  k_bounds<<<(cE_NODE + 1 + 255) / 256, 256, 0, stream>>>(ii, bnd);
  k_hist<<<(cE_DOM + 255) / 256, 256, 0, stream>>>(dme + cE_DOM, cnt);
  k_scan1<<<(cN_SRC + 255) / 256, 256, 0, stream>>>(cnt, bsum, excl);
  k_scan2<<<1, 256, 0, stream>>>(bsum, (cN_SRC + 255) / 256);
  k_scan3<<<(cN_SRC + 1 + 255) / 256, 256, 0, stream>>>(excl, bsum, offs, cursor);
  k_scatter<<<(cE_DOM + 255) / 256, 256, 0, stream>>>(dme + cE_DOM, cursor, inv);
  k_edge2<<<neb, 256, 0, stream>>>((const unsigned*)xw, nme, bnd,
                                   (const unsigned*)xsl, (const unsigned*)ylin,
                                   dme, dme + cE_DOM, inv,
                                   (unsigned*)msg, partials);
  k_bnred1<<<64, 256, 0, stream>>>(partials, part2, neb);
  k_bnfinal<<<1, 256, 0, stream>>>(part2, bnw, bnb, ssbuf);
  k_out2<<<(cN_Y + 3) / 4, 256, 0, stream>>>((const unsigned*)msg, offs, ssbuf, out);
}